// Round 2
// baseline (275.118 us; speedup 1.0000x reference)
//
#include <hip/hip_runtime.h>
#include <hip/hip_cooperative_groups.h>
#include <stdint.h>

namespace cg = cooperative_groups;

#define NBOX 8000
#define NPAD 8192

// ---- workspace layout (bytes) ----
#define ECNT_OFF 0                           // u32 edge count
#define ALIVE_OFF 0x1000                     // 128 x u64 alive bitmap
#define SB(i)    (0x10000 + (size_t)(i) * 0x8000)
// sorted-by-rank arrays (float[8192] each):
// 0 bx, 1 by, 2 bw, 3 bh, 4 conf, 5 cls, 6 x1, 7 y1, 8 x2, 9 y2, 10 area
#define EDGE_OFF (size_t)0x200000            // u32 edges (i<<13|j)

__device__ __forceinline__ float sigmoidf_(float x) {
    return 1.0f / (1.0f + expf(-x));
}

// Single cooperative kernel: 256 blocks x 512 threads, 1 block/CU.
// Phase A: fused decode-conf + ballot-rank + scatter-to-sorted (as before).
// Phase B: suppression-edge tiles (4096 tiles grid-strided, 2 per block-iter).
// Phase C: Jacobi fixed-point NMS (block 0).
// Phase D: coalesced zero-or-copy output (32 ranks per block).
__global__ __launch_bounds__(512, 1) void yolo_nms_fused(const float* __restrict__ x,
                                                         const float* __restrict__ anchors,
                                                         unsigned char* __restrict__ ws,
                                                         float* __restrict__ out) {
    __shared__ union {
        struct { unsigned long long keys[NPAD]; int partial[256]; } a;   // 65.5 KB
        struct { float cst[2][7][64]; } b;                                // 3.5 KB
        struct { unsigned int eld[16384];
                 unsigned long long valid[128], alive[128], supp[128];
                 int flag; } c;                                           // 67 KB
        struct { float o[192]; } d;
    } u;

    cg::grid_group grid = cg::this_grid();
    int tid  = threadIdx.x;
    int lane = tid & 63;
    int wv   = tid >> 6;                         // wave 0..7
    int blk  = blockIdx.x;                       // 256 blocks

    // ================= phase A: sort + decode =================
    {
        if (blk == 0 && tid == 0) *(unsigned int*)(ws + ECNT_OFF) = 0u;

        // all 8192 keys -> LDS (coalesced conf loads + sigmoid)
        for (int t = tid; t < NPAD; t += 512) {
            unsigned long long k;
            if (t < NBOX) {
                int a = t / 1600, pos = t - a * 1600;
                float c = sigmoidf_(x[a * 40000 + 4 * 1600 + pos]);
                k = ((unsigned long long)__float_as_uint(c) << 32) | (unsigned long long)(8191 - t);
            } else {
                k = (unsigned long long)(8191 - t);  // pads sort last
            }
            u.a.keys[t] = k;
        }
        __syncthreads();

        // ballot-rank: wave wv holds segment wv in 16 u64 regs/lane
        unsigned long long kj[16];
        #pragma unroll
        for (int c = 0; c < 16; ++c) kj[c] = u.a.keys[(wv << 10) + (c << 6) + lane];
        unsigned long long ki = u.a.keys[(blk << 5) + lane];

        int vout = 0;
        for (int ii = 0; ii < 32; ++ii) {
            unsigned int klo = (unsigned int)__builtin_amdgcn_readlane((int)(unsigned int)ki, ii);
            unsigned int khi = (unsigned int)__builtin_amdgcn_readlane((int)(unsigned int)(ki >> 32), ii);
            unsigned long long kib = ((unsigned long long)khi << 32) | (unsigned long long)klo;
            int c = 0;
            #pragma unroll
            for (int ch = 0; ch < 16; ++ch)
                c += __popcll(__ballot(kj[ch] > kib));
            vout = (lane == ii) ? c : vout;
        }
        if (lane < 32) u.a.partial[(wv << 5) + lane] = vout;
        __syncthreads();

        // wave 0 lanes 0..31: sum partials, decode, scatter-write sorted arrays
        if (wv == 0 && lane < 32) {
            int r = 0;
            #pragma unroll
            for (int s = 0; s < 8; ++s) r += u.a.partial[(s << 5) + lane];

            int i = (blk << 5) + lane;
            float bx = 0.f, by = 0.f, bw = 0.f, bh = 0.f, conf = 0.f, cls = -1.0f;
            if (i < NBOX) {
                int a = i / 1600, pos = i - a * 1600;
                int gy = pos / 40, gx = pos - gy * 40;
                const float* p = x + (size_t)a * 40000 + pos;
                float tx = sigmoidf_(p[0]);
                float ty = sigmoidf_(p[1600]);
                float tw = p[2 * 1600];
                float th = p[3 * 1600];
                conf = sigmoidf_(p[4 * 1600]);
                float best = -1.0f; int bi = 0;
                #pragma unroll
                for (int c = 0; c < 20; ++c) {   // first-max wins == jnp.argmax
                    float v = sigmoidf_(p[(5 + c) * 1600]);
                    if (v > best) { best = v; bi = c; }
                }
                float aw = anchors[a * 2 + 0];
                float ah = anchors[a * 2 + 1];
                bx = (tx + (float)gx) * 8.0f;
                by = (ty + (float)gy) * 8.0f;
                bw = expf(tw) * aw * 8.0f;
                bh = expf(th) * ah * 8.0f;
                cls = (float)bi;
            }
            {
            #pragma clang fp contract(off)
                float x1 = bx - bw / 2.0f, y1 = by - bh / 2.0f;
                float x2 = bx + bw / 2.0f, y2 = by + bh / 2.0f;
                float ar = fabsf((x2 - x1) * (y2 - y1));
                ((float*)(ws + SB(0)))[r]  = bx;  ((float*)(ws + SB(1)))[r]  = by;
                ((float*)(ws + SB(2)))[r]  = bw;  ((float*)(ws + SB(3)))[r]  = bh;
                ((float*)(ws + SB(4)))[r]  = conf; ((float*)(ws + SB(5)))[r] = cls;
                ((float*)(ws + SB(6)))[r]  = x1;  ((float*)(ws + SB(7)))[r]  = y1;
                ((float*)(ws + SB(8)))[r]  = x2;  ((float*)(ws + SB(9)))[r]  = y2;
                ((float*)(ws + SB(10)))[r] = ar;
            }
        }
    }
    __threadfence();
    grid.sync();

    // ================= phase B: suppression edges =================
    {
    #pragma clang fp contract(off)
        const float* sconf = (const float*)(ws + SB(4));
        const float* sx1 = (const float*)(ws + SB(6));
        const float* sy1 = (const float*)(ws + SB(7));
        const float* sx2 = (const float*)(ws + SB(8));
        const float* sy2 = (const float*)(ws + SB(9));
        const float* sar = (const float*)(ws + SB(10));
        const float* scl = (const float*)(ws + SB(5));

        int h  = tid >> 8;                       // half-block 0/1 (4 waves each)
        int tl = tid & 255;

        for (int k = 0; k < 8; ++k) {
            int t  = k * 512 + (blk << 1) + h;   // tile id in [0, 4096)
            int iy = t >> 7, w = t & 127;
            int i0 = iy << 8, j0 = w << 6;
            bool skip = (sconf[i0] <= 0.5f) || (sconf[j0] <= 0.5f) || (j0 + 64 <= i0);

            if (!skip && tl < 64) {
                int j = j0 + tl;
                u.b.cst[h][0][tl] = sx1[j]; u.b.cst[h][1][tl] = sy1[j];
                u.b.cst[h][2][tl] = sx2[j]; u.b.cst[h][3][tl] = sy2[j];
                u.b.cst[h][4][tl] = sar[j]; u.b.cst[h][5][tl] = scl[j];
                u.b.cst[h][6][tl] = sconf[j];
            }
            __syncthreads();

            if (!skip) {
                int i = i0 + tl;
                unsigned long long word = 0;
                if (sconf[i] > 0.5f && j0 + 64 > i + 1) {
                    float x1i = sx1[i], y1i = sy1[i], x2i = sx2[i], y2i = sy2[i];
                    float ai = sar[i], ci = scl[i];
                    for (int jj = 0; jj < 64; ++jj) {
                        int j = j0 + jj;
                        if (j <= i) continue;
                        if (u.b.cst[h][6][jj] <= 0.5f) continue;   // col invalid
                        if (u.b.cst[h][5][jj] != ci) continue;     // class mismatch
                        float iw = fminf(x2i, u.b.cst[h][2][jj]) - fmaxf(x1i, u.b.cst[h][0][jj]);
                        iw = fmaxf(iw, 0.0f);
                        float ih = fminf(y2i, u.b.cst[h][3][jj]) - fmaxf(y1i, u.b.cst[h][1][jj]);
                        ih = fmaxf(ih, 0.0f);
                        float inter = iw * ih;
                        float denom = ai + u.b.cst[h][4][jj] - inter + 1e-6f;
                        if (inter / denom >= 0.5f) word |= (1ull << jj);
                    }
                }
                // wave-aggregated edge emission (all 64 lanes of the wave)
                int pc = __popcll(word);
                int scan = pc;
                #pragma unroll
                for (int d = 1; d < 64; d <<= 1) {
                    int tt = __shfl_up(scan, d, 64);
                    if (lane >= d) scan += tt;
                }
                int total = __shfl(scan, 63, 64);
                if (total > 0) {
                    unsigned int base = 0;
                    if (lane == 63)
                        base = atomicAdd((unsigned int*)(ws + ECNT_OFF), (unsigned int)total);
                    base = (unsigned int)__shfl((int)base, 63, 64);
                    unsigned int off = base + (unsigned int)(scan - pc);
                    unsigned int* edges = (unsigned int*)(ws + EDGE_OFF);
                    unsigned long long tw = word;
                    while (tw) {
                        int bit = __builtin_ctzll(tw);
                        tw &= tw - 1ull;
                        edges[off++] = ((unsigned int)i << 13) | (unsigned int)(j0 + bit);
                    }
                }
            }
            __syncthreads();
        }
    }
    __threadfence();
    grid.sync();

    // ================= phase C: Jacobi fixed-point NMS (block 0) =================
    if (blk == 0) {
        unsigned int E = *(const unsigned int*)(ws + ECNT_OFF);
        const unsigned int* edges = (const unsigned int*)(ws + EDGE_OFF);
        const float* sconf = (const float*)(ws + SB(4));

        for (int c = tid >> 6; c < 128; c += 8) {
            unsigned long long m = __ballot(sconf[(c << 6) + lane] > 0.5f);
            if (lane == 0) u.c.valid[c] = m;
        }
        bool uselds = (E <= 16384u);
        if (uselds)
            for (unsigned int e = tid; e < E; e += 512) u.c.eld[e] = edges[e];
        __syncthreads();
        if (tid < 128) u.c.alive[tid] = u.c.valid[tid];
        __syncthreads();

        for (;;) {
            if (tid < 128) u.c.supp[tid] = 0ull;
            __syncthreads();
            for (unsigned int e = tid; e < E; e += 512) {
                unsigned int uu = uselds ? u.c.eld[e] : edges[e];
                unsigned int i = uu >> 13, j = uu & 8191u;
                if ((u.c.alive[i >> 6] >> (i & 63)) & 1ull)
                    atomicOr(&u.c.supp[j >> 6], 1ull << (j & 63));
            }
            if (tid == 0) u.c.flag = 0;
            __syncthreads();
            if (tid < 128) {
                unsigned long long na = u.c.valid[tid] & ~u.c.supp[tid];
                if (na != u.c.alive[tid]) { u.c.alive[tid] = na; u.c.flag = 1; }
            }
            __syncthreads();
            if (!u.c.flag) break;
        }

        if (tid < 128) ((unsigned long long*)(ws + ALIVE_OFF))[tid] = u.c.alive[tid];
        __threadfence();
    }
    grid.sync();

    // ================= phase D: output (32 ranks per block) =================
    {
        const unsigned long long* alv = (const unsigned long long*)(ws + ALIVE_OFF);
        int r0 = blk << 5;
        if (tid < 32) {
            int r = r0 + tid;
            float v0 = 0.f, v1 = 0.f, v2 = 0.f, v3 = 0.f, v4 = 0.f, v5 = 0.f;
            if ((alv[r >> 6] >> (r & 63)) & 1ull) {
                v0 = ((const float*)(ws + SB(0)))[r];
                v1 = ((const float*)(ws + SB(1)))[r];
                v2 = ((const float*)(ws + SB(2)))[r];
                v3 = ((const float*)(ws + SB(3)))[r];
                v4 = ((const float*)(ws + SB(4)))[r];
                v5 = ((const float*)(ws + SB(5)))[r];
            }
            u.d.o[tid * 6 + 0] = v0; u.d.o[tid * 6 + 1] = v1; u.d.o[tid * 6 + 2] = v2;
            u.d.o[tid * 6 + 3] = v3; u.d.o[tid * 6 + 4] = v4; u.d.o[tid * 6 + 5] = v5;
        }
        __syncthreads();
        int base = r0 * 6;
        if (tid < 192 && base + tid < NBOX * 6) out[base + tid] = u.d.o[tid];
    }
}

extern "C" void kernel_launch(void* const* d_in, const int* in_sizes, int n_in,
                              void* d_out, int out_size, void* d_ws, size_t ws_size,
                              hipStream_t stream) {
    const float* x       = (const float*)d_in[0];
    const float* anchors = (const float*)d_in[1];
    float* out           = (float*)d_out;
    unsigned char* ws    = (unsigned char*)d_ws;

    void* args[] = { (void*)&x, (void*)&anchors, (void*)&ws, (void*)&out };
    hipLaunchCooperativeKernel((const void*)yolo_nms_fused, dim3(256), dim3(512),
                               args, 0, stream);
}

// Round 3
// 152.102 us; speedup vs baseline: 1.8088x; 1.8088x over previous
//
#include <hip/hip_runtime.h>
#include <stdint.h>

#define NBOX 8000
#define NPAD 8192

// ---- workspace layout (bytes) ----
#define ECNT_OFF 0                           // u32 edge count (zeroed by K1)
#define DONE_OFF 64                          // u32 finished-block count (zeroed by K1)
#define SB(i)    (0x10000 + (size_t)(i) * 0x8000)
// sorted-by-rank arrays (float[8192] each):
// 0 bx, 1 by, 2 bw, 3 bh, 4 conf, 5 cls, 6 x1, 7 y1, 8 x2, 9 y2, 10 area
#define EDGE_OFF (size_t)0x200000            // u32 edges (i<<13|j)

__device__ __forceinline__ float sigmoidf_(float x) {
    return 1.0f / (1.0f + expf(-x));
}

// ================= K1: fused decode-conf + ballot-rank + scatter-to-sorted =================
// Block b owns source boxes [b*32, b*32+32)  (256 blocks -> all 256 CUs).
// Phase 1: 512 threads materialize ALL 8192 keys into LDS once. ONE barrier.
// Phase 2: ballot-rank (16 u64 regs/lane per wave segment; readlane broadcast;
//          v_cmp+ballot+popc on scalar pipe). 17 LDS reads per wave total.
// Phase 3: wave 0 lanes 0..31 sum partials, decode 32 consecutive boxes
//          (coalesced channel loads), scatter-write the sorted arrays.
// Validity downstream = sconf[r] > 0.5 (sorted => equivalent to r < V).
__global__ __launch_bounds__(512) void sort_decode_kernel(const float* __restrict__ x,
                                                          const float* __restrict__ anchors,
                                                          unsigned char* __restrict__ ws) {
    __shared__ unsigned long long keys[NPAD];    // 64 KB
    __shared__ int partial[256];                 // 8 waves x 32 rows
    int tid  = threadIdx.x;
    int lane = tid & 63;
    int wv   = tid >> 6;                         // wave 0..7
    int b    = blockIdx.x;                       // 256 blocks

    if (b == 0 && tid == 0) {
        *(unsigned int*)(ws + ECNT_OFF) = 0u;    // edge count for K2
        *(unsigned int*)(ws + DONE_OFF) = 0u;    // done-block count for K2
    }

    // ---- phase 1: all keys -> LDS (16 coalesced loads/thread) ----
    for (int t = tid; t < NPAD; t += 512) {
        unsigned long long k;
        if (t < NBOX) {
            int a = t / 1600, pos = t - a * 1600;
            float c = sigmoidf_(x[a * 40000 + 4 * 1600 + pos]);
            k = ((unsigned long long)__float_as_uint(c) << 32) | (unsigned long long)(8191 - t);
        } else {
            k = (unsigned long long)(8191 - t);  // pads sort last (conf bits = 0)
        }
        keys[t] = k;
    }
    __syncthreads();

    // ---- phase 2: ballot-rank; wave wv vs segment wv ----
    unsigned long long kj[16];
    #pragma unroll
    for (int c = 0; c < 16; ++c) kj[c] = keys[(wv << 10) + (c << 6) + lane];
    unsigned long long ki = keys[(b << 5) + lane];

    int vout = 0;                                // lane L ends with partial for row L
    for (int ii = 0; ii < 32; ++ii) {
        unsigned int klo = (unsigned int)__builtin_amdgcn_readlane((int)(unsigned int)ki, ii);
        unsigned int khi = (unsigned int)__builtin_amdgcn_readlane((int)(unsigned int)(ki >> 32), ii);
        unsigned long long kib = ((unsigned long long)khi << 32) | (unsigned long long)klo;
        int c = 0;
        #pragma unroll
        for (int ch = 0; ch < 16; ++ch)
            c += __popcll(__ballot(kj[ch] > kib));
        vout = (lane == ii) ? c : vout;
    }
    if (lane < 32) partial[(wv << 5) + lane] = vout;
    __syncthreads();

    // ---- phase 3: wave 0 lanes 0..31 sum partials, decode, scatter-write ----
    if (wv == 0 && lane < 32) {
        int r = 0;
        #pragma unroll
        for (int s = 0; s < 8; ++s) r += partial[(s << 5) + lane];

        int i = (b << 5) + lane;                 // source box owned by this lane
        float bx = 0.f, by = 0.f, bw = 0.f, bh = 0.f, conf = 0.f, cls = -1.0f;
        if (i < NBOX) {                          // full decode (coalesced channel loads)
            int a = i / 1600, pos = i - a * 1600;
            int gy = pos / 40, gx = pos - gy * 40;
            const float* p = x + (size_t)a * 40000 + pos;
            float tx = sigmoidf_(p[0]);
            float ty = sigmoidf_(p[1600]);
            float tw = p[2 * 1600];
            float th = p[3 * 1600];
            conf = sigmoidf_(p[4 * 1600]);
            float best = -1.0f; int bi = 0;
            #pragma unroll
            for (int c = 0; c < 20; ++c) {       // first-max wins, matches jnp.argmax
                float v = sigmoidf_(p[(5 + c) * 1600]);
                if (v > best) { best = v; bi = c; }
            }
            float aw = anchors[a * 2 + 0];
            float ah = anchors[a * 2 + 1];
            bx = (tx + (float)gx) * 8.0f;
            by = (ty + (float)gy) * 8.0f;
            bw = expf(tw) * aw * 8.0f;
            bh = expf(th) * ah * 8.0f;
            cls = (float)bi;
        }
        {
        #pragma clang fp contract(off)
            float x1 = bx - bw / 2.0f, y1 = by - bh / 2.0f;
            float x2 = bx + bw / 2.0f, y2 = by + bh / 2.0f;
            float ar = fabsf((x2 - x1) * (y2 - y1));   // ref: recomputed from corners
            ((float*)(ws + SB(0)))[r]  = bx;  ((float*)(ws + SB(1)))[r]  = by;
            ((float*)(ws + SB(2)))[r]  = bw;  ((float*)(ws + SB(3)))[r]  = bh;
            ((float*)(ws + SB(4)))[r]  = conf; ((float*)(ws + SB(5)))[r] = cls;
            ((float*)(ws + SB(6)))[r]  = x1;  ((float*)(ws + SB(7)))[r]  = y1;
            ((float*)(ws + SB(8)))[r]  = x2;  ((float*)(ws + SB(9)))[r]  = y2;
            ((float*)(ws + SB(10)))[r] = ar;
        }
    }
}

// ================= K2: suppression edges + last-block NMS + output =================
// 256 blocks x 512 threads. Each block processes 16 of the 4096 (256-row x
// 64-col) tiles as 2 half-block tiles x 8 iterations (verified round-2
// structure). After its tiles, each block release-fences and bumps a done
// counter; the LAST block (all edges globally visible) runs the Jacobi
// fixed-point NMS and writes the output — no extra dispatches, no grid.sync.
__global__ __launch_bounds__(512) void mask_nms_out_kernel(unsigned char* __restrict__ ws,
                                                           float* __restrict__ out) {
    __shared__ float cst[2][7][64];                       // 3.5 KB mask staging
    __shared__ unsigned long long valid[128], alive[128], supp[128];
    __shared__ int flag;
    __shared__ int lastBlk;
    __shared__ float obuf[2][3072];                       // 24 KB output staging

    int tid  = threadIdx.x;
    int lane = tid & 63;
    int blk  = blockIdx.x;                                // 256 blocks

    const float* sconf = (const float*)(ws + SB(4));
    const float* sx1 = (const float*)(ws + SB(6));
    const float* sy1 = (const float*)(ws + SB(7));
    const float* sx2 = (const float*)(ws + SB(8));
    const float* sy2 = (const float*)(ws + SB(9));
    const float* sar = (const float*)(ws + SB(10));
    const float* scl = (const float*)(ws + SB(5));

    // ---------------- phase 1: suppression-edge tiles ----------------
    {
    #pragma clang fp contract(off)
        int h  = tid >> 8;                       // half-block 0/1 (4 waves each)
        int tl = tid & 255;

        for (int k = 0; k < 8; ++k) {
            int t  = k * 512 + (blk << 1) + h;   // tile id in [0, 4096)
            int iy = t >> 7, w = t & 127;
            int i0 = iy << 8, j0 = w << 6;
            bool skip = (sconf[i0] <= 0.5f) || (sconf[j0] <= 0.5f) || (j0 + 64 <= i0);

            if (!skip && tl < 64) {
                int j = j0 + tl;
                cst[h][0][tl] = sx1[j]; cst[h][1][tl] = sy1[j];
                cst[h][2][tl] = sx2[j]; cst[h][3][tl] = sy2[j];
                cst[h][4][tl] = sar[j]; cst[h][5][tl] = scl[j];
                cst[h][6][tl] = sconf[j];
            }
            __syncthreads();

            if (!skip) {
                int i = i0 + tl;
                unsigned long long word = 0;
                if (sconf[i] > 0.5f && j0 + 64 > i + 1) {  // row i valid
                    float x1i = sx1[i], y1i = sy1[i], x2i = sx2[i], y2i = sy2[i];
                    float ai = sar[i], ci = scl[i];
                    for (int jj = 0; jj < 64; ++jj) {
                        int j = j0 + jj;
                        if (j <= i) continue;
                        if (cst[h][6][jj] <= 0.5f) continue;   // col j invalid
                        if (cst[h][5][jj] != ci) continue;     // class mismatch
                        float iw = fminf(x2i, cst[h][2][jj]) - fmaxf(x1i, cst[h][0][jj]);
                        iw = fmaxf(iw, 0.0f);
                        float ih = fminf(y2i, cst[h][3][jj]) - fmaxf(y1i, cst[h][1][jj]);
                        ih = fmaxf(ih, 0.0f);
                        float inter = iw * ih;
                        float denom = ai + cst[h][4][jj] - inter + 1e-6f;
                        if (inter / denom >= 0.5f) word |= (1ull << jj);
                    }
                }
                // wave-aggregated edge emission (all 64 lanes of the wave)
                int pc = __popcll(word);
                int scan = pc;
                #pragma unroll
                for (int d = 1; d < 64; d <<= 1) {
                    int tt = __shfl_up(scan, d, 64);
                    if (lane >= d) scan += tt;
                }
                int total = __shfl(scan, 63, 64);
                if (total > 0) {
                    unsigned int base = 0;
                    if (lane == 63)
                        base = atomicAdd((unsigned int*)(ws + ECNT_OFF), (unsigned int)total);
                    base = (unsigned int)__shfl((int)base, 63, 64);
                    unsigned int off = base + (unsigned int)(scan - pc);   // exclusive prefix
                    unsigned int* edges = (unsigned int*)(ws + EDGE_OFF);
                    unsigned long long tw = word;
                    while (tw) {
                        int bit = __builtin_ctzll(tw);
                        tw &= tw - 1ull;
                        edges[off++] = ((unsigned int)i << 13) | (unsigned int)(j0 + bit);
                    }
                }
            }
            __syncthreads();
        }
    }

    // ---------------- completion detection: last block continues ----------------
    __threadfence();                              // release this block's edge writes
    if (tid == 0)
        lastBlk = (atomicAdd((unsigned int*)(ws + DONE_OFF), 1u) == 255u);
    __syncthreads();
    if (!lastBlk) return;
    __threadfence();                              // acquire: see all blocks' edges

    // ---------------- phase 2: Jacobi fixed-point NMS (this block only) ----------------
    // Greedy NMS == unique fixed point of a[j] = valid[j] & ~OR_{i<j, edge} a[i].
    {
        unsigned int E = *(const unsigned int*)(ws + ECNT_OFF);
        const unsigned int* edges = (const unsigned int*)(ws + EDGE_OFF);

        for (int c = tid >> 6; c < 128; c += 8) {
            unsigned long long m = __ballot(sconf[(c << 6) + lane] > 0.5f);
            if (lane == 0) valid[c] = m;
        }
        __syncthreads();
        if (tid < 128) alive[tid] = valid[tid];
        __syncthreads();

        for (;;) {
            if (tid < 128) supp[tid] = 0ull;
            __syncthreads();
            for (unsigned int e = tid; e < E; e += 512) {
                unsigned int uu = edges[e];
                unsigned int i = uu >> 13, j = uu & 8191u;
                if ((alive[i >> 6] >> (i & 63)) & 1ull)
                    atomicOr(&supp[j >> 6], 1ull << (j & 63));
            }
            if (tid == 0) flag = 0;
            __syncthreads();
            if (tid < 128) {
                unsigned long long na = valid[tid] & ~supp[tid];
                if (na != alive[tid]) { alive[tid] = na; flag = 1; }
            }
            __syncthreads();
            if (!flag) break;
        }
    }

    // ---------------- phase 3: output (16 chunks of 512 ranks, dbuf LDS transpose) ----------------
    {
        const float* s0 = (const float*)(ws + SB(0));
        const float* s1 = (const float*)(ws + SB(1));
        const float* s2 = (const float*)(ws + SB(2));
        const float* s3 = (const float*)(ws + SB(3));
        const float* s4 = (const float*)(ws + SB(4));
        const float* s5 = (const float*)(ws + SB(5));

        for (int c = 0; c < 16; ++c) {
            int r = (c << 9) + tid;               // rank 0..8191
            int p = c & 1;
            float v0 = 0.f, v1 = 0.f, v2 = 0.f, v3 = 0.f, v4 = 0.f, v5 = 0.f;
            if ((alive[r >> 6] >> (r & 63)) & 1ull) {
                v0 = s0[r]; v1 = s1[r]; v2 = s2[r];
                v3 = s3[r]; v4 = s4[r]; v5 = s5[r];
            }
            obuf[p][tid * 6 + 0] = v0; obuf[p][tid * 6 + 1] = v1;
            obuf[p][tid * 6 + 2] = v2; obuf[p][tid * 6 + 3] = v3;
            obuf[p][tid * 6 + 4] = v4; obuf[p][tid * 6 + 5] = v5;
            __syncthreads();
            int basef = c * 3072;                 // float index of chunk start
            const float4* src = (const float4*)obuf[p];
            float4* dst = (float4*)(out + basef);
            #pragma unroll
            for (int tq = tid; tq < 768; tq += 512)
                if ((basef >> 2) + tq < (NBOX * 6) / 4) dst[tq] = src[tq];
        }
    }
}

extern "C" void kernel_launch(void* const* d_in, const int* in_sizes, int n_in,
                              void* d_out, int out_size, void* d_ws, size_t ws_size,
                              hipStream_t stream) {
    const float* x       = (const float*)d_in[0];
    const float* anchors = (const float*)d_in[1];
    float* out           = (float*)d_out;
    unsigned char* ws    = (unsigned char*)d_ws;

    sort_decode_kernel<<<256, 512, 0, stream>>>(x, anchors, ws);
    mask_nms_out_kernel<<<256, 512, 0, stream>>>(ws, out);
}